// Round 1
// baseline (1191.345 us; speedup 1.0000x reference)
//
#include <hip/hip_runtime.h>
#include <stdint.h>

// =====================================================================
// Gps fused pipeline on MI355X (gfx950), split-bf16 MFMA GEMMs.
//
// Math restructuring:
//   G1 = (f1 @ W1b^T)*0.5  [4096x256]  ; B1 = [G1 ; W1a^T]  K=4352
//   h  = lrelu( [adj1 | feat0] @ B1 )            (feat0 = gather(featm, seed))
//   G2 = (f2 @ W2b^T)*0.5  [2048x256]  ; B2 = [G2 ; W2a^T]  K=2304
//   emb= lrelu( [mean4(adj2) | h] @ B2 )         (4-row mean folded into staging)
//
// Precision: every operand split into bf16 hi + lo (x ~= hi + lo, 16-bit
// mantissa). 3 MFMA products per frag pair (hh, lh, hl) -> ~1e-5 rel err.
//
// LDS layouts are k-blocked [K/8][cols][8] so each lane's MFMA fragment
// (8 consecutive k of one row/col) is one contiguous 16B ds_read_b128,
// and B tiles are contiguous 32KB chunks -> global_load_lds direct copy.
// =====================================================================

typedef unsigned short u16;
typedef unsigned int   u32;
typedef __attribute__((ext_vector_type(8))) short bf16x8;   // 8 bf16 in 4 VGPRs
typedef __attribute__((ext_vector_type(4))) float f32x4;
typedef __attribute__((ext_vector_type(4))) float float4_t;
typedef __attribute__((ext_vector_type(4))) u16   u16x4;

#define DEVI __device__ __forceinline__

constexpr int BM = 64;    // M rows per block
constexpr int BN = 256;   // full output width
constexpr int BK = 32;    // K per step (one 16x16x32 MFMA)

DEVI u16 f2bf(float f) {                       // RTNE f32 -> bf16 bits
  union { float f; u32 u; } v; v.f = f;
  return (u16)((v.u + 0x7fffu + ((v.u >> 16) & 1u)) >> 16);
}
DEVI float bf2f(u16 h) {
  union { u32 u; float f; } v; v.u = ((u32)h) << 16; return v.f;
}
DEVI void split2(float x, u16& hi, u16& lo) {  // x ~= hi + lo (bf16 pair)
  hi = f2bf(x);
  lo = f2bf(x - bf2f(hi));
}

DEVI void gll16(const u16* g, u16* l) {        // async global->LDS, 16B/lane
  __builtin_amdgcn_global_load_lds(
      (__attribute__((address_space(1))) u32*)g,
      (__attribute__((address_space(3))) u32*)l, 16, 0, 0);
}

// ---------------------------------------------------------------------
// prep: transposed+split copies of W1/W2 quadrants into blocked layouts.
//   job0: Wt1 = W1b^T   (B operand for G1 GEMM)
//   job1: B1 tail rows 4096+k = W1a^T
//   job2: Wt2 = W2b^T
//   job3: B2 tail rows 2048+k = W2a^T
// blocked addr of (row r, col n): ((r>>3)*256 + n)*8 + (r&7)
// ---------------------------------------------------------------------
__global__ __launch_bounds__(256) void prep_kernel(
    const float* __restrict__ W1, const float* __restrict__ W2,
    u16* __restrict__ Wt1h, u16* __restrict__ Wt1l,
    u16* __restrict__ Wt2h, u16* __restrict__ Wt2l,
    u16* __restrict__ B1h,  u16* __restrict__ B1l,
    u16* __restrict__ B2h,  u16* __restrict__ B2l)
{
  const int idx = blockIdx.x * 256 + threadIdx.x;   // 0 .. 262143
  const int job = idx >> 16;
  const int e   = idx & 65535;
  const int n   = e >> 8;        // output col (0..255)
  const int k   = e & 255;       // source k  (0..255)
  u16 hi, lo;
  if (job == 0) {
    split2(W1[n * 512 + 256 + k], hi, lo);
    const int o = ((k >> 3) * 256 + n) * 8 + (k & 7);
    Wt1h[o] = hi; Wt1l[o] = lo;
  } else if (job == 1) {
    split2(W1[n * 512 + k], hi, lo);
    const int r = 4096 + k;
    const int o = ((r >> 3) * 256 + n) * 8 + (r & 7);
    B1h[o] = hi; B1l[o] = lo;
  } else if (job == 2) {
    split2(W2[n * 512 + 256 + k], hi, lo);
    const int o = ((k >> 3) * 256 + n) * 8 + (k & 7);
    Wt2h[o] = hi; Wt2l[o] = lo;
  } else {
    split2(W2[n * 512 + k], hi, lo);
    const int r = 2048 + k;
    const int o = ((r >> 3) * 256 + n) * 8 + (r & 7);
    B2h[o] = hi; B2l[o] = lo;
  }
}

// ---------------------------------------------------------------------
// A-staging modes:
//  0: plain fp32 row-major A1 (lda1), split on stage
//  1: gathered rows featm[seed[m]] (256 cols), split on stage
//  2: mean of 4 consecutive rows of A1 (*0.25), split on stage
//  3: pre-split bf16 pair A3h/A3l, row-major 256 cols, passthrough
// ---------------------------------------------------------------------
template<int MODE>
DEVI void loadA(const float* __restrict__ A1, int lda1,
                const float* __restrict__ featm, const int* __restrict__ seed,
                const u16* __restrict__ A3h, const u16* __restrict__ A3l,
                int tileM, int kphase, int sm, int skl,
                float4_t& r0, float4_t& r1, float4_t& r2, float4_t& r3,
                u16x4& rh, u16x4& rl)
{
  const int kk = kphase + skl;
  if constexpr (MODE == 0) {
    r0 = *(const float4_t*)&A1[(size_t)(tileM + sm) * lda1 + kk];
  } else if constexpr (MODE == 1) {
    const int s = seed[tileM + sm];
    r0 = *(const float4_t*)&featm[(size_t)s * 256 + kk];
  } else if constexpr (MODE == 2) {
    const float* p = &A1[(size_t)(tileM + sm) * 4 * lda1 + kk];
    r0 = *(const float4_t*)p;
    r1 = *(const float4_t*)(p + lda1);
    r2 = *(const float4_t*)(p + 2 * lda1);
    r3 = *(const float4_t*)(p + 3 * lda1);
  } else {
    const size_t o = (size_t)(tileM + sm) * 256 + kk;
    rh = *(const u16x4*)&A3h[o];
    rl = *(const u16x4*)&A3l[o];
  }
}

template<int MODE>
DEVI void writeA(float4_t r0, float4_t r1, float4_t r2, float4_t r3,
                 u16x4 rh, u16x4 rl, u16* dh, u16* dl)
{
  if constexpr (MODE == 3) {
    *(u16x4*)dh = rh;
    *(u16x4*)dl = rl;
  } else {
    if constexpr (MODE == 2) r0 = (r0 + r1 + r2 + r3) * 0.25f;
    u16x4 h, l;
#pragma unroll
    for (int j = 0; j < 4; ++j) { u16 a, b; split2(r0[j], a, b); h[j] = a; l[j] = b; }
    *(u16x4*)dh = h;
    *(u16x4*)dl = l;
  }
}

DEVI void stageB_fn(const u16* __restrict__ Bh, const u16* __restrict__ Bl,
                    int it, u16 (*sBb)[8192], int tid)
{
  const size_t base = (size_t)it * 8192;      // 4 kb-rows * 2048 elems
  const int wv = tid >> 6, ln = tid & 63;
#pragma unroll
  for (int c = 0; c < 2; ++c) {
    const size_t o = base + (size_t)c * 4096 + (size_t)wv * 512;
    gll16(Bh + o + ln * 8, &sBb[0][c * 4096 + wv * 512]);
    gll16(Bl + o + ln * 8, &sBb[1][c * 4096 + wv * 512]);
  }
}

// ---------------------------------------------------------------------
// Generic split-bf16 GEMM: C[BM x 256] per block, K walked in BK=32 steps.
// A source = mode AM1 for steps < kt_split, mode AM2 after (kphase rebased).
// B source = one blocked array covering the whole K range.
// OM: 0 = *0.5, split-store blocked (produces G1/G2 inside B1/B2)
//     1 = lrelu, fp32 row-major store (final emb)
//     2 = lrelu, split-store row-major (h pair)
// ---------------------------------------------------------------------
template<int AM1, int AM2, int OM>
__global__ __launch_bounds__(512)
void gemm_split(const float* __restrict__ A1, int lda1,
                const float* __restrict__ featm, const int* __restrict__ seed,
                const u16* __restrict__ A3h, const u16* __restrict__ A3l,
                const u16* __restrict__ Bh, const u16* __restrict__ Bl,
                int kt_total, int kt_split,
                float* __restrict__ Of, u16* __restrict__ Oh, u16* __restrict__ Ol)
{
  // A: [4 kb][64 m][8] per hi/lo ; B: [4 kb][256 n][8] per hi/lo ; dbuf
  __shared__ u16 sA[2][2][2048];   // 16 KB
  __shared__ u16 sB[2][2][8192];   // 64 KB

  const int tid   = threadIdx.x;
  const int tileM = blockIdx.x * BM;
  const int lane  = tid & 63;
  const int wave  = tid >> 6;          // 8 waves: 2 (M) x 4 (N)
  const int wm    = wave >> 2;
  const int wn    = wave & 3;
  const int l15   = lane & 15;
  const int l4    = lane >> 4;

  // staging decomposition: 512 threads, each owns 4 elements (half a 16B slot)
  const int slot = tid >> 1;           // 0..255 : kb*64 + m
  const int half = tid & 1;
  const int sm   = slot & 63;
  const int skb  = slot >> 6;
  const int skl  = skb * 8 + half * 4; // k-local 0..28

  f32x4 acc[2][4] = {};
  int cur = 0;

  // prologue: stage step 0 into buffer 0 (step 0 is always phase AM1)
  {
    stageB_fn(Bh, Bl, 0, sB[0], tid);
    float4_t r0{}, r1{}, r2{}, r3{}; u16x4 rh{}, rl{};
    loadA<AM1>(A1, lda1, featm, seed, A3h, A3l, tileM, 0, sm, skl,
               r0, r1, r2, r3, rh, rl);
    writeA<AM1>(r0, r1, r2, r3, rh, rl,
                &sA[0][0][slot * 8 + half * 4], &sA[0][1][slot * 8 + half * 4]);
  }
  __syncthreads();

  for (int it = 0; it < kt_total; ++it) {
    const int  nb = cur ^ 1;
    const bool hn = (it + 1) < kt_total;
    const bool p1 = (it + 1) < kt_split;

    // ---- issue next-step staging loads early (B: async LDS, A: to regs)
    float4_t r0{}, r1{}, r2{}, r3{}; u16x4 rh{}, rl{};
    if (hn) {
      stageB_fn(Bh, Bl, it + 1, sB[nb], tid);
      if (p1) loadA<AM1>(A1, lda1, featm, seed, A3h, A3l, tileM,
                         (it + 1) * BK, sm, skl, r0, r1, r2, r3, rh, rl);
      else    loadA<AM2>(A1, lda1, featm, seed, A3h, A3l, tileM,
                         (it + 1 - kt_split) * BK, sm, skl, r0, r1, r2, r3, rh, rl);
    }

    // ---- compute current buffer
    bf16x8 ah[2], al[2], bh[4], bl[4];
#pragma unroll
    for (int mf = 0; mf < 2; ++mf) {
      const int sa = (l4 * 64 + wm * 32 + mf * 16 + l15) * 8;
      ah[mf] = *(const bf16x8*)&sA[cur][0][sa];
      al[mf] = *(const bf16x8*)&sA[cur][1][sa];
    }
#pragma unroll
    for (int nf = 0; nf < 4; ++nf) {
      const int sb = (l4 * 256 + wn * 64 + nf * 16 + l15) * 8;
      bh[nf] = *(const bf16x8*)&sB[cur][0][sb];
      bl[nf] = *(const bf16x8*)&sB[cur][1][sb];
    }
#pragma unroll
    for (int mf = 0; mf < 2; ++mf)
#pragma unroll
      for (int nf = 0; nf < 4; ++nf) {
        acc[mf][nf] = __builtin_amdgcn_mfma_f32_16x16x32_bf16(ah[mf], bh[nf], acc[mf][nf], 0, 0, 0);
        acc[mf][nf] = __builtin_amdgcn_mfma_f32_16x16x32_bf16(al[mf], bh[nf], acc[mf][nf], 0, 0, 0);
        acc[mf][nf] = __builtin_amdgcn_mfma_f32_16x16x32_bf16(ah[mf], bl[nf], acc[mf][nf], 0, 0, 0);
      }

    // ---- finish staging: convert + LDS write (loads had MFMA time to land)
    if (hn) {
      u16* dh = &sA[nb][0][slot * 8 + half * 4];
      u16* dl = &sA[nb][1][slot * 8 + half * 4];
      if (p1) writeA<AM1>(r0, r1, r2, r3, rh, rl, dh, dl);
      else    writeA<AM2>(r0, r1, r2, r3, rh, rl, dh, dl);
    }
    __syncthreads();
    cur = nb;
  }

  // ---- epilogue. C/D frag: col = lane&15, row = (lane>>4)*4 + reg (m89)
#pragma unroll
  for (int mf = 0; mf < 2; ++mf)
#pragma unroll
    for (int nf = 0; nf < 4; ++nf)
#pragma unroll
      for (int j = 0; j < 4; ++j) {
        const int row = tileM + wm * 32 + mf * 16 + l4 * 4 + j;
        const int col = wn * 64 + nf * 16 + l15;
        float v = acc[mf][nf][j];
        if constexpr (OM == 0) {
          v *= 0.5f;                             // fold reference's *0.5
          u16 hi, lo; split2(v, hi, lo);
          const size_t o = ((size_t)(row >> 3) * 256 + col) * 8 + (row & 7);
          Oh[o] = hi; Ol[o] = lo;
        } else if constexpr (OM == 1) {
          v = v >= 0.f ? v : 0.01f * v;
          Of[(size_t)row * 256 + col] = v;
        } else {
          v = v >= 0.f ? v : 0.01f * v;
          u16 hi, lo; split2(v, hi, lo);
          const size_t o = (size_t)row * 256 + col;
          Oh[o] = hi; Ol[o] = lo;
        }
      }
}

// ---------------------------------------------------------------------
extern "C" void kernel_launch(void* const* d_in, const int* in_sizes, int n_in,
                              void* d_out, int out_size, void* d_ws, size_t ws_size,
                              hipStream_t stream)
{
  const float* featm = (const float*)d_in[0];   // [100000,256]
  const float* adj1  = (const float*)d_in[1];   // [16384,4096]
  const float* f1    = (const float*)d_in[2];   // [4096,256]
  const float* adj2  = (const float*)d_in[3];   // [65536,2048]
  const float* f2    = (const float*)d_in[4];   // [2048,256]
  const float* W1    = (const float*)d_in[5];   // [256,512]
  const float* W2    = (const float*)d_in[6];   // [256,512]
  const int*   seed  = (const int*)d_in[7];     // [16384]
  float* out = (float*)d_out;                   // [16384,256]

  // workspace carve-up (24.2 MB total)
  char* p = (char*)d_ws;
  u16* B1h  = (u16*)p; p += (size_t)4352 * 256 * 2;
  u16* B1l  = (u16*)p; p += (size_t)4352 * 256 * 2;
  u16* B2h  = (u16*)p; p += (size_t)2304 * 256 * 2;
  u16* B2l  = (u16*)p; p += (size_t)2304 * 256 * 2;
  u16* Wt1h = (u16*)p; p += (size_t)256 * 256 * 2;
  u16* Wt1l = (u16*)p; p += (size_t)256 * 256 * 2;
  u16* Wt2h = (u16*)p; p += (size_t)256 * 256 * 2;
  u16* Wt2l = (u16*)p; p += (size_t)256 * 256 * 2;
  u16* Hh   = (u16*)p; p += (size_t)16384 * 256 * 2;
  u16* Hl   = (u16*)p; p += (size_t)16384 * 256 * 2;

  // K0: weight transposes/splits (also fills B1/B2 tails with W1a^T/W2a^T)
  prep_kernel<<<1024, 256, 0, stream>>>(W1, W2, Wt1h, Wt1l, Wt2h, Wt2l,
                                        B1h, B1l, B2h, B2l);

  // K1a: G1 = f1 @ W1b^T * 0.5  -> B1 rows [0,4096)
  gemm_split<0, 0, 0><<<64, 512, 0, stream>>>(
      f1, 256, nullptr, nullptr, nullptr, nullptr,
      Wt1h, Wt1l, 8, 8, nullptr, B1h, B1l);

  // K1b: G2 = f2 @ W2b^T * 0.5  -> B2 rows [0,2048)
  gemm_split<0, 0, 0><<<32, 512, 0, stream>>>(
      f2, 256, nullptr, nullptr, nullptr, nullptr,
      Wt2h, Wt2l, 8, 8, nullptr, B2h, B2l);

  // K2: h = lrelu([adj1 | gather(featm,seed)] @ B1) -> split pair (Hh,Hl)
  gemm_split<0, 1, 2><<<256, 512, 0, stream>>>(
      adj1, 4096, featm, seed, nullptr, nullptr,
      B1h, B1l, 136, 128, nullptr, Hh, Hl);

  // K3: emb = lrelu([mean4(adj2) | h] @ B2) -> d_out fp32
  gemm_split<2, 3, 1><<<256, 512, 0, stream>>>(
      adj2, 2048, nullptr, nullptr, Hh, Hl,
      B2h, B2l, 72, 64, out, nullptr, nullptr);
}